// Round 1
// baseline (220.822 us; speedup 1.0000x reference)
//
#include <hip/hip_runtime.h>

// x: (B=8, L=8192, D=512) fp32.  out: (B, L/4=2048, D) fp32.
// out[b,i,d] = sum_{l=0..4(i+1)-1} x[b,l,d] / (4(i+1))
//
// Two-pass chunked scan over L per (b,d) column:
//   phase 1: per-chunk column sums -> d_ws
//   phase 2: prefix of chunk sums + in-chunk running sum -> out
//
// Thread mapping: tid -> (b, chunk c, d4) with d4 (float4 index along D)
// in the low bits so wave lanes access contiguous 1 KiB segments.

#define BB   8
#define LL   8192
#define DD4  128            // D / 4 (float4 granularity)
#define NC   128            // chunks along L
#define CL   (LL / NC)      // 64 rows per chunk
#define OL   (LL / 4)       // 2048 output rows

__global__ __launch_bounds__(256) void ds_phase1(const float4* __restrict__ x,
                                                 float4* __restrict__ sums) {
    int tid = blockIdx.x * blockDim.x + threadIdx.x;
    int d4 = tid & (DD4 - 1);
    int c  = (tid >> 7) & (NC - 1);
    int b  = tid >> 14;

    const float4* p = x + ((b * LL + c * CL) * DD4 + d4);
    float sx = 0.f, sy = 0.f, sz = 0.f, sw = 0.f;
    #pragma unroll 8
    for (int j = 0; j < CL; ++j) {
        float4 v = p[j * DD4];
        sx += v.x; sy += v.y; sz += v.z; sw += v.w;
    }
    // layout: sums[b][c][d4] so phase-2 prefix reads are lane-coalesced
    sums[(b * NC + c) * DD4 + d4] = make_float4(sx, sy, sz, sw);
}

__global__ __launch_bounds__(256) void ds_phase2(const float4* __restrict__ x,
                                                 const float4* __restrict__ sums,
                                                 float4* __restrict__ out) {
    int tid = blockIdx.x * blockDim.x + threadIdx.x;
    int d4 = tid & (DD4 - 1);
    int c  = (tid >> 7) & (NC - 1);
    int b  = tid >> 14;

    // exclusive prefix over preceding chunk sums (wave-uniform trip count,
    // coalesced reads; sums array is 2 MiB -> L2-resident)
    float rx = 0.f, ry = 0.f, rz = 0.f, rw = 0.f;
    const float4* sp = sums + b * NC * DD4 + d4;
    #pragma unroll 4
    for (int c2 = 0; c2 < c; ++c2) {
        float4 v = sp[c2 * DD4];
        rx += v.x; ry += v.y; rz += v.z; rw += v.w;
    }

    const float4* p = x + ((b * LL + c * CL) * DD4 + d4);
    float4* o = out + ((b * OL + c * (CL / 4)) * DD4 + d4);
    int base = c * CL;

    #pragma unroll 4
    for (int j = 0; j < CL; j += 4) {
        float4 v0 = p[(j + 0) * DD4];
        float4 v1 = p[(j + 1) * DD4];
        float4 v2 = p[(j + 2) * DD4];
        float4 v3 = p[(j + 3) * DD4];
        rx += v0.x + v1.x + v2.x + v3.x;
        ry += v0.y + v1.y + v2.y + v3.y;
        rz += v0.z + v1.z + v2.z + v3.z;
        rw += v0.w + v1.w + v2.w + v3.w;
        float inv = 1.0f / (float)(base + j + 4);   // count = l+1 = base+j+3+1
        o[(j >> 2) * DD4] = make_float4(rx * inv, ry * inv, rz * inv, rw * inv);
    }
}

extern "C" void kernel_launch(void* const* d_in, const int* in_sizes, int n_in,
                              void* d_out, int out_size, void* d_ws, size_t ws_size,
                              hipStream_t stream) {
    const float4* x = (const float4*)d_in[0];
    float4* out = (float4*)d_out;
    float4* sums = (float4*)d_ws;      // B*NC*DD4 float4 = 2 MiB

    const int total = BB * NC * DD4;   // 131072 threads
    const int block = 256;
    const int grid  = total / block;   // 512 blocks

    ds_phase1<<<grid, block, 0, stream>>>(x, sums);
    ds_phase2<<<grid, block, 0, stream>>>(x, sums, out);
}